// Round 1
// baseline (115.479 us; speedup 1.0000x reference)
//
#include <hip/hip_runtime.h>

// PHM embedding: out[t, q*256+j] = sum_k a[k, p, q] * s[k, i, j]
//   where v = input[t], p = v / 12565, i = v % 12565.
// VOCAB=50257, EMB=1024, PHM=4, VOCAB_PAD=50260 -> NROW = 12565, EMBQ = 256.
// Inputs (setup_inputs order): input int32[8*2048], a f32[4*4*4], s f32[4*12565*256].
// Output: f32[8*2048*1024].

#define NROW 12565
#define EMBQ 256
#define NTOK (8 * 2048)

__global__ __launch_bounds__(256) void phm_embed_kernel(
    const int* __restrict__ idx,
    const float* __restrict__ a,
    const float* __restrict__ s,
    float* __restrict__ out)
{
    __shared__ float a_sh[64];
    const int tid = threadIdx.x;
    if (tid < 64) a_sh[tid] = a[tid];
    __syncthreads();

    const int t = blockIdx.x;           // one token per block
    const int v = idx[t];               // 0 .. 50256
    const int p = v / NROW;             // 0..3 (magic-mul)
    const int i = v - p * NROW;         // 0..12564
    const int q = tid >> 6;             // wave id = output quarter
    const int j0 = (tid & 63) << 2;     // 4 consecutive j per lane

    // a[k,p,q] is wave-uniform (broadcast LDS read, conflict-free)
    const float a0 = a_sh[0 * 16 + p * 4 + q];
    const float a1 = a_sh[1 * 16 + p * 4 + q];
    const float a2 = a_sh[2 * 16 + p * 4 + q];
    const float a3 = a_sh[3 * 16 + p * 4 + q];

    const float* srow = s + (size_t)i * EMBQ + j0;
    const float4 v0 = *(const float4*)(srow + (size_t)0 * NROW * EMBQ);
    const float4 v1 = *(const float4*)(srow + (size_t)1 * NROW * EMBQ);
    const float4 v2 = *(const float4*)(srow + (size_t)2 * NROW * EMBQ);
    const float4 v3 = *(const float4*)(srow + (size_t)3 * NROW * EMBQ);

    float4 o;
    o.x = a0 * v0.x + a1 * v1.x + a2 * v2.x + a3 * v3.x;
    o.y = a0 * v0.y + a1 * v1.y + a2 * v2.y + a3 * v3.y;
    o.z = a0 * v0.z + a1 * v1.z + a2 * v2.z + a3 * v3.z;
    o.w = a0 * v0.w + a1 * v1.w + a2 * v2.w + a3 * v3.w;

    *(float4*)(out + (size_t)t * 1024 + (size_t)tid * 4) = o;
}

extern "C" void kernel_launch(void* const* d_in, const int* in_sizes, int n_in,
                              void* d_out, int out_size, void* d_ws, size_t ws_size,
                              hipStream_t stream) {
    const int*   idx = (const int*)d_in[0];
    const float* a   = (const float*)d_in[1];
    const float* s   = (const float*)d_in[2];
    float*       out = (float*)d_out;

    phm_embed_kernel<<<NTOK, 256, 0, stream>>>(idx, a, s, out);
}

// Round 2
// 112.025 us; speedup vs baseline: 1.0308x; 1.0308x over previous
//
#include <hip/hip_runtime.h>

// PHM embedding: out[t, q*256+j] = sum_k a[k, p, q] * s[k, i, j]
//   v = input[t], p = v / 12565, i = v % 12565.
// VOCAB=50257, EMB=1024, PHM=4, VOCAB_PAD=50260 -> NROW=12565, EMBQ=256.
// Inputs: input int32[16384], a f32[64], s f32[4*12565*256]. Output f32[16384*1024].
//
// R1: one WAVE per token (R0 used one wave per token-QUARTER, so every s-row
// was loaded 4x). The 4 s-row float4s are reused in registers for all 4
// output quarters. 4 tokens/wave, unrolled in pairs for MLP (~8 KiB in
// flight per wave). 1024 blocks x 256 thr = 16 waves/CU resident.

#define NROW 12565
#define NTOK (8 * 2048)
#define TPW 4                      // tokens per wave
#define NBLK (NTOK / (4 * TPW))    // 1024 blocks

__global__ __launch_bounds__(256) void phm_embed_kernel(
    const int* __restrict__ idx,
    const float* __restrict__ a,
    const float* __restrict__ s,
    float* __restrict__ out)
{
    __shared__ float a_sh[64];
    const int tid = threadIdx.x;
    if (tid < 64) a_sh[tid] = a[tid];
    __syncthreads();

    const size_t KSTR = (size_t)NROW * 256;   // k-plane stride in s
    const int wave = blockIdx.x * 4 + (tid >> 6);
    const int lane = tid & 63;
    const int j0 = lane << 2;                 // 4 consecutive floats per lane
    const int t0 = wave * TPW;

    #pragma unroll
    for (int n = 0; n < TPW; n += 2) {
        const int tA = t0 + n;
        const int tB = t0 + n + 1;
        const int vA = idx[tA];               // wave-uniform broadcast load
        const int vB = idx[tB];
        const int pA = vA / NROW;  const int iA = vA - pA * NROW;
        const int pB = vB / NROW;  const int iB = vB - pB * NROW;

        const float* sA = s + (size_t)iA * 256 + j0;
        const float* sB = s + (size_t)iB * 256 + j0;

        // issue all 8 loads (8 KiB/wave in flight) before any use
        const float4 A0 = *(const float4*)(sA + 0 * KSTR);
        const float4 A1 = *(const float4*)(sA + 1 * KSTR);
        const float4 A2 = *(const float4*)(sA + 2 * KSTR);
        const float4 A3 = *(const float4*)(sA + 3 * KSTR);
        const float4 B0 = *(const float4*)(sB + 0 * KSTR);
        const float4 B1 = *(const float4*)(sB + 1 * KSTR);
        const float4 B2 = *(const float4*)(sB + 2 * KSTR);
        const float4 B3 = *(const float4*)(sB + 3 * KSTR);

        float* oA = out + (size_t)tA * 1024 + j0;
        float* oB = out + (size_t)tB * 1024 + j0;

        #pragma unroll
        for (int q = 0; q < 4; ++q) {
            const float c0 = a_sh[0 * 16 + pA * 4 + q];
            const float c1 = a_sh[1 * 16 + pA * 4 + q];
            const float c2 = a_sh[2 * 16 + pA * 4 + q];
            const float c3 = a_sh[3 * 16 + pA * 4 + q];
            float4 o;
            o.x = c0 * A0.x + c1 * A1.x + c2 * A2.x + c3 * A3.x;
            o.y = c0 * A0.y + c1 * A1.y + c2 * A2.y + c3 * A3.y;
            o.z = c0 * A0.z + c1 * A1.z + c2 * A2.z + c3 * A3.z;
            o.w = c0 * A0.w + c1 * A1.w + c2 * A2.w + c3 * A3.w;
            *(float4*)(oA + q * 256) = o;
        }
        #pragma unroll
        for (int q = 0; q < 4; ++q) {
            const float c0 = a_sh[0 * 16 + pB * 4 + q];
            const float c1 = a_sh[1 * 16 + pB * 4 + q];
            const float c2 = a_sh[2 * 16 + pB * 4 + q];
            const float c3 = a_sh[3 * 16 + pB * 4 + q];
            float4 o;
            o.x = c0 * B0.x + c1 * B1.x + c2 * B2.x + c3 * B3.x;
            o.y = c0 * B0.y + c1 * B1.y + c2 * B2.y + c3 * B3.y;
            o.z = c0 * B0.z + c1 * B1.z + c2 * B2.z + c3 * B3.z;
            o.w = c0 * B0.w + c1 * B1.w + c2 * B2.w + c3 * B3.w;
            *(float4*)(oB + q * 256) = o;
        }
    }
}

extern "C" void kernel_launch(void* const* d_in, const int* in_sizes, int n_in,
                              void* d_out, int out_size, void* d_ws, size_t ws_size,
                              hipStream_t stream) {
    const int*   idx = (const int*)d_in[0];
    const float* a   = (const float*)d_in[1];
    const float* s   = (const float*)d_in[2];
    float*       out = (float*)d_out;

    phm_embed_kernel<<<NBLK, 256, 0, stream>>>(idx, a, s, out);
}

// Round 4
// 111.333 us; speedup vs baseline: 1.0372x; 1.0062x over previous
//
#include <hip/hip_runtime.h>

// PHM embedding: out[t, q*256+j] = sum_k a[k, p, q] * s[k, i, j]
//   v = input[t], p = v / 12565, i = v % 12565.
// VOCAB=50257, EMB=1024, PHM=4 -> NROW=12565.
// Inputs: input int32[16384], a f32[64], s f32[4*12565*256]. Output f32[16384*1024].
//
// R3 = R2 with native ext_vector_type float4 (HIP_vector_type rejected by
// __builtin_nontemporal_store):
// (a) nontemporal 16B stores -- 64 MiB output was streaming through the
//     32 MiB aggregate L2, evicting s lines between gather reads;
// (b) full occupancy: TPW=2, 2048 blocks x 256 thr = 32 waves/CU.
// One wave per token; s-row vectors reused in regs for all 4 output quarters.

typedef float v4f __attribute__((ext_vector_type(4)));

#define NROW 12565
#define NTOK (8 * 2048)
#define TPW 2                      // tokens per wave
#define NBLK (NTOK / (4 * TPW))    // 2048 blocks

__global__ __launch_bounds__(256) void phm_embed_kernel(
    const int* __restrict__ idx,
    const float* __restrict__ a,
    const float* __restrict__ s,
    float* __restrict__ out)
{
    __shared__ float a_sh[64];
    const int tid = threadIdx.x;
    if (tid < 64) a_sh[tid] = a[tid];
    __syncthreads();

    const size_t KSTR = (size_t)NROW * 256;   // k-plane stride in s
    const int wave = blockIdx.x * 4 + (tid >> 6);
    const int lane = tid & 63;
    const int j0 = lane << 2;                 // 4 consecutive floats per lane
    const int t0 = wave * TPW;

    const int tA = t0;
    const int tB = t0 + 1;
    const int vA = idx[tA];                   // wave-uniform broadcast load
    const int vB = idx[tB];
    const int pA = vA / NROW;  const int iA = vA - pA * NROW;
    const int pB = vB / NROW;  const int iB = vB - pB * NROW;

    const float* sA = s + (size_t)iA * 256 + j0;
    const float* sB = s + (size_t)iB * 256 + j0;

    // issue all 8 loads (8 KiB/wave in flight) before any use
    const v4f A0 = *(const v4f*)(sA + 0 * KSTR);
    const v4f A1 = *(const v4f*)(sA + 1 * KSTR);
    const v4f A2 = *(const v4f*)(sA + 2 * KSTR);
    const v4f A3 = *(const v4f*)(sA + 3 * KSTR);
    const v4f B0 = *(const v4f*)(sB + 0 * KSTR);
    const v4f B1 = *(const v4f*)(sB + 1 * KSTR);
    const v4f B2 = *(const v4f*)(sB + 2 * KSTR);
    const v4f B3 = *(const v4f*)(sB + 3 * KSTR);

    v4f* oA = (v4f*)(out + (size_t)tA * 1024 + j0);
    v4f* oB = (v4f*)(out + (size_t)tB * 1024 + j0);

    #pragma unroll
    for (int q = 0; q < 4; ++q) {
        const float c0 = a_sh[0 * 16 + pA * 4 + q];
        const float c1 = a_sh[1 * 16 + pA * 4 + q];
        const float c2 = a_sh[2 * 16 + pA * 4 + q];
        const float c3 = a_sh[3 * 16 + pA * 4 + q];
        v4f o = c0 * A0 + c1 * A1 + c2 * A2 + c3 * A3;
        __builtin_nontemporal_store(o, oA + q * 64);   // q*256 floats = q*64 v4f
    }
    #pragma unroll
    for (int q = 0; q < 4; ++q) {
        const float c0 = a_sh[0 * 16 + pB * 4 + q];
        const float c1 = a_sh[1 * 16 + pB * 4 + q];
        const float c2 = a_sh[2 * 16 + pB * 4 + q];
        const float c3 = a_sh[3 * 16 + pB * 4 + q];
        v4f o = c0 * B0 + c1 * B1 + c2 * B2 + c3 * B3;
        __builtin_nontemporal_store(o, oB + q * 64);
    }
}

extern "C" void kernel_launch(void* const* d_in, const int* in_sizes, int n_in,
                              void* d_out, int out_size, void* d_ws, size_t ws_size,
                              hipStream_t stream) {
    const int*   idx = (const int*)d_in[0];
    const float* a   = (const float*)d_in[1];
    const float* s   = (const float*)d_in[2];
    float*       out = (float*)d_out;

    phm_embed_kernel<<<NBLK, 256, 0, stream>>>(idx, a, s, out);
}